// Round 10
// baseline (46.663 us; speedup 1.0000x reference)
//
#include <hip/hip_runtime.h>
#include <hip/hip_bf16.h>

// Single-head causal attention, B=4096, T=64, C=128, H=64.
// Grid 512 x 256thr (2 blocks/CU), NB=8 batches/block, 2-barrier pipeline.
// R10: W held in 48 persistent VGPRs per wave (wave owns h-tiles 3w..3w+2,
// R8-validated incl. flipped-operand v-tiles) -> W LDS traffic zero.
// x staged in LDS as bf16 (reg-load + cvt + ds_write_b128), halving R9's
// LDS-read volume (68->36 KB/wave-iter; R9 was LDS-read co-limited).
// x[i+1] staged after the QKV barrier; xr[i+2] issued mid-iter so the
// syncthreads vmcnt-drain lands ~600cy after issue (hidden under attn).

typedef __bf16 bf16_t;
typedef __bf16 bf16x8 __attribute__((ext_vector_type(8)));
typedef __bf16 bf16x4 __attribute__((ext_vector_type(4)));
typedef float  f32x4  __attribute__((ext_vector_type(4)));

#define X_OFF   0        // x bf16 [64][128], 256B rows, swizzled; 16 KB
#define Q_OFF   16384    // Q [t][h] 64x64 bf16, swizzled, 8 KB
#define K_OFF   24576    // K [s][h] 8 KB
#define VT_OFF  32768    // VT [h][t] 8 KB
#define P_OFF   40960    // per-wave P scratch: w*2048, 16x64 bf16, 8 KB
#define LDS_BYTES 49152  // 48 KB

__device__ __forceinline__ int swz(int off, int row) { return off ^ ((row & 7) << 4); }

__device__ __forceinline__ bf16x8 pack8(float4 a, float4 b) {
    bf16x8 r;
    r[0] = (bf16_t)a.x; r[1] = (bf16_t)a.y; r[2] = (bf16_t)a.z; r[3] = (bf16_t)a.w;
    r[4] = (bf16_t)b.x; r[5] = (bf16_t)b.y; r[6] = (bf16_t)b.z; r[7] = (bf16_t)b.w;
    return r;
}

__global__ __launch_bounds__(256) __attribute__((amdgpu_waves_per_eu(2, 2)))
void head_attn_kernel(const float* __restrict__ x,
                      const float* __restrict__ Wq,
                      const float* __restrict__ Wk,
                      const float* __restrict__ Wv,
                      float* __restrict__ out,
                      int NB)
{
    __shared__ __align__(16) char smem[LDS_BYTES];
    const int tid  = threadIdx.x;
    const int w    = tid >> 6;
    const int lane = tid & 63;
    const int l15  = lane & 15;
    const int lg   = lane >> 4;
    const int t    = w * 16 + l15;      // lane's query/time row (attention)
    const int tile0 = 3 * w;            // this wave's first h-tile
    char* pscr = smem + P_OFF + w * 2048;

    // x staging role: thread owns quarter-row (row tx, f32 cols qx*32..+32)
    const int tx = tid >> 2;
    const int qx = tid & 3;
    const size_t b0 = (size_t)blockIdx.x * NB;
    const float* xbase = x + b0 * 8192 + tx * 128 + qx * 32;

    // ---- prologue: issue batch-0 x loads ----------------------------------
    float4 xr[8];
    #pragma unroll
    for (int k = 0; k < 8; ++k) xr[k] = *(const float4*)(xbase + k * 4);

    // ---- W fragments for this wave's 3 h-tiles: persistent registers ------
    bf16x8 wfr[3][4];
    #pragma unroll
    for (int j = 0; j < 3; ++j) {
        int hg = (tile0 + j) * 16 + l15;
        const float* wr = (hg < 64)  ? Wq + hg * 128
                        : (hg < 128) ? Wk + (hg - 64) * 128
                                     : Wv + (hg - 128) * 128;
        #pragma unroll
        for (int ks = 0; ks < 4; ++ks) {
            float4 a = *(const float4*)(wr + ks * 32 + lg * 8);
            float4 c = *(const float4*)(wr + ks * 32 + lg * 8 + 4);
            wfr[j][ks] = pack8(a, c);
        }
    }

    // ---- stage x[0]; issue xr(1) ------------------------------------------
    #pragma unroll
    for (int c = 0; c < 4; ++c)
        *(bf16x8*)(smem + X_OFF + swz(tx * 256 + qx * 64 + c * 16, tx)) =
            pack8(xr[2 * c], xr[2 * c + 1]);
    if (NB > 1) {
        #pragma unroll
        for (int k = 0; k < 8; ++k) xr[k] = *(const float4*)(xbase + 8192 + k * 4);
    }
    __syncthreads();

    for (int i = 0; i < NB; ++i) {
        // ------------- QKV: wave's 3 h-tiles x all 4 t-tiles ---------------
        // tile<8 (q/k): mfma(wfr, xf) -> lane = t, regs = h   [R8-validated]
        // tile>=8 (v):  mfma(xf, wfr) -> lane = h, regs = t   [R8-validated]
        f32x4 acc[3][4];
        #pragma unroll
        for (int j = 0; j < 3; ++j)
            #pragma unroll
            for (int tt = 0; tt < 4; ++tt) acc[j][tt] = (f32x4){0.f, 0.f, 0.f, 0.f};

        #pragma unroll
        for (int ks = 0; ks < 4; ++ks) {
            bf16x8 xf[4];
            #pragma unroll
            for (int tt = 0; tt < 4; ++tt) {
                int tr = tt * 16 + l15;
                xf[tt] = *(const bf16x8*)(smem + X_OFF + swz(tr * 256 + ks * 64 + lg * 16, tr));
            }
            #pragma unroll
            for (int j = 0; j < 3; ++j) {
                if (tile0 + j < 8) {
                    #pragma unroll
                    for (int tt = 0; tt < 4; ++tt)
                        acc[j][tt] = __builtin_amdgcn_mfma_f32_16x16x32_bf16(
                            wfr[j][ks], xf[tt], acc[j][tt], 0, 0, 0);
                } else {
                    #pragma unroll
                    for (int tt = 0; tt < 4; ++tt)
                        acc[j][tt] = __builtin_amdgcn_mfma_f32_16x16x32_bf16(
                            xf[tt], wfr[j][ks], acc[j][tt], 0, 0, 0);
                }
            }
        }

        // write q/k ([t][h], b64) and v (VT [h][t], b64)
        #pragma unroll
        for (int j = 0; j < 3; ++j) {
            int tile = tile0 + j;
            if (tile < 8) {
                int base = (tile < 4) ? Q_OFF : K_OFF;
                int h0 = (tile & 3) * 16 + lg * 4;
                #pragma unroll
                for (int tt = 0; tt < 4; ++tt) {
                    int tr = tt * 16 + l15;
                    bf16x4 pk;
                    pk[0] = (bf16_t)acc[j][tt][0]; pk[1] = (bf16_t)acc[j][tt][1];
                    pk[2] = (bf16_t)acc[j][tt][2]; pk[3] = (bf16_t)acc[j][tt][3];
                    *(bf16x4*)(smem + base + swz(tr * 128 + h0 * 2, tr)) = pk;
                }
            } else {
                int hv = (tile - 8) * 16 + l15;
                #pragma unroll
                for (int tt = 0; tt < 4; ++tt) {
                    int t0 = tt * 16 + lg * 4;
                    bf16x4 pk;
                    pk[0] = (bf16_t)acc[j][tt][0]; pk[1] = (bf16_t)acc[j][tt][1];
                    pk[2] = (bf16_t)acc[j][tt][2]; pk[3] = (bf16_t)acc[j][tt][3];
                    *(bf16x4*)(smem + VT_OFF + swz(hv * 128 + t0 * 2, hv)) = pk;
                }
            }
        }
        __syncthreads();   // q/k/v visible; x region now dead

        // ------------- stage x[i+1] (overlaps nothing it conflicts with) ---
        if (i + 1 < NB) {
            #pragma unroll
            for (int c = 0; c < 4; ++c)
                *(bf16x8*)(smem + X_OFF + swz(tx * 256 + qx * 64 + c * 16, tx)) =
                    pack8(xr[2 * c], xr[2 * c + 1]);
        }
        // issue xr(i+2): consumed next iter; drained at this iter's end-barrier
        // ~600cy after issue (hidden under the attention phase below)
        if (i + 2 < NB) {
            const float* xn = xbase + (size_t)(i + 2) * 8192;
            #pragma unroll
            for (int k = 0; k < 8; ++k) xr[k] = *(const float4*)(xn + k * 4);
        }

        // ------------- S^T = K . q^T : lane = col t (own row), regs = s ----
        f32x4 sacc[4];
        #pragma unroll
        for (int st = 0; st < 4; ++st) sacc[st] = (f32x4){0.f, 0.f, 0.f, 0.f};
        #pragma unroll
        for (int ks = 0; ks < 2; ++ks) {
            int h0 = ks * 32 + lg * 8;
            bf16x8 qf = *(const bf16x8*)(smem + Q_OFF + swz(t * 128 + h0 * 2, t));
            #pragma unroll
            for (int st = 0; st < 4; ++st) {
                int s = st * 16 + l15;
                bf16x8 kf = *(const bf16x8*)(smem + K_OFF + swz(s * 128 + h0 * 2, s));
                sacc[st] = __builtin_amdgcn_mfma_f32_16x16x32_bf16(kf, qf, sacc[st], 0, 0, 0);
            }
        }

        // ------------- softmax: each lane owns full row t ------------------
        float p[4][4];
        float m = -1e30f;
        #pragma unroll
        for (int st = 0; st < 4; ++st)
            #pragma unroll
            for (int r = 0; r < 4; ++r) {
                int s = st * 16 + lg * 4 + r;
                float v = sacc[st][r] * 0.125f;
                v = (s <= t) ? v : -1e30f;     // causal
                p[st][r] = v;
                m = fmaxf(m, v);
            }
        m = fmaxf(m, __shfl_xor(m, 16));
        m = fmaxf(m, __shfl_xor(m, 32));
        float sum = 0.f;
        #pragma unroll
        for (int st = 0; st < 4; ++st)
            #pragma unroll
            for (int r = 0; r < 4; ++r) {
                float e = __expf(p[st][r] - m);
                p[st][r] = e;
                sum += e;
            }
        sum += __shfl_xor(sum, 16);
        sum += __shfl_xor(sum, 32);
        float inv = 1.0f / sum;
        #pragma unroll
        for (int st = 0; st < 4; ++st) {
            bf16x4 pk;
            pk[0] = (bf16_t)(p[st][0] * inv); pk[1] = (bf16_t)(p[st][1] * inv);
            pk[2] = (bf16_t)(p[st][2] * inv); pk[3] = (bf16_t)(p[st][3] * inv);
            *(bf16x4*)(pscr + swz(l15 * 128 + (st * 16 + lg * 4) * 2, l15)) = pk;
        }
        // wave-private scratch: same-wave write->read, in-order, no barrier

        // ------------- out^T = V^T . P^T (swapped): lane = col t -----------
        f32x4 oacc[4];
        #pragma unroll
        for (int ht = 0; ht < 4; ++ht) oacc[ht] = (f32x4){0.f, 0.f, 0.f, 0.f};
        #pragma unroll
        for (int ks = 0; ks < 2; ++ks) {
            int s0 = ks * 32 + lg * 8;
            bf16x8 pf = *(const bf16x8*)(pscr + swz(l15 * 128 + s0 * 2, l15));
            #pragma unroll
            for (int ht = 0; ht < 4; ++ht) {
                int h = ht * 16 + l15;
                bf16x8 vf = *(const bf16x8*)(smem + VT_OFF + swz(h * 128 + s0 * 2, h));
                oacc[ht] = __builtin_amdgcn_mfma_f32_16x16x32_bf16(vf, pf, oacc[ht], 0, 0, 0);
            }
        }

        float* ob = out + (b0 + i) * 4096 + t * 64 + lg * 4;
        #pragma unroll
        for (int ht = 0; ht < 4; ++ht)
            *(float4*)(ob + ht * 16) =
                (float4){oacc[ht][0], oacc[ht][1], oacc[ht][2], oacc[ht][3]};

        __syncthreads();   // attn reads done + x[i+1] visible for next QKV
    }
}

extern "C" void kernel_launch(void* const* d_in, const int* in_sizes, int n_in,
                              void* d_out, int out_size, void* d_ws, size_t ws_size,
                              hipStream_t stream) {
    const float* x  = (const float*)d_in[0];
    const float* Wq = (const float*)d_in[1];
    const float* Wk = (const float*)d_in[2];
    const float* Wv = (const float*)d_in[3];
    float* out = (float*)d_out;
    int B = in_sizes[0] / (64 * 128);   // 4096
    int grid = 512;                     // 2 blocks/CU
    int NB = B / grid;                  // 8 batches per block
    head_attn_kernel<<<grid, 256, 0, stream>>>(x, Wq, Wk, Wv, out, NB);
}

// Round 11
// 44.405 us; speedup vs baseline: 1.0509x; 1.0509x over previous
//
#include <hip/hip_runtime.h>
#include <hip/hip_bf16.h>

// Single-head causal attention, B=4096, T=64, C=128, H=64.
// Grid 512 x 256thr (2 blocks/CU), NB=8 batches per block.
// R11 = R9 (best measured: 44.4us) + ONE change: raw barriers.
// __syncthreads() emits s_waitcnt vmcnt(0) before s_barrier, force-draining
// the cross-batch x prefetch (issued ~1.5Kcy earlier, several-Kcy HBM
// latency under load) every iteration -> ~10Kcy/iter stall. Replaced with
// lgkmcnt(0)-only barriers: LDS publishes still sync; global loads/stores
// stay in flight across barriers and are waited at USE (next iteration).

typedef __bf16 bf16_t;
typedef __bf16 bf16x8 __attribute__((ext_vector_type(8)));
typedef __bf16 bf16x4 __attribute__((ext_vector_type(4)));
typedef float  f32x4  __attribute__((ext_vector_type(4)));

#define WL_OFF  0        // W bf16 fragments: byte ((ks*12+j)*64+lane)*16, 48 KB
#define K_OFF   49152    // K [s][h] 64x64 bf16, swizzled, 8 KB
#define VT_OFF  57344    // VT [h][t] 64x64 bf16, swizzled, 8 KB
#define QS_OFF  65536    // per-wave scratch (q then P): w*2048, 16x64 bf16, 8 KB
#define LDS_BYTES 73728  // 72 KB -> 2 blocks/CU

__device__ __forceinline__ int swz(int off, int row) { return off ^ ((row & 7) << 4); }

// Barrier that publishes LDS writes but does NOT drain vmcnt: in-flight
// global loads/stores (only touch the owning wave's registers / global mem)
// survive across it. asm memory clobbers pin LDS ops to the correct side.
__device__ __forceinline__ void lds_barrier() {
    asm volatile("s_waitcnt lgkmcnt(0)" ::: "memory");
    __builtin_amdgcn_s_barrier();
    asm volatile("" ::: "memory");
}

__device__ __forceinline__ bf16x8 pack8(float4 a, float4 b) {
    bf16x8 r;
    r[0] = (bf16_t)a.x; r[1] = (bf16_t)a.y; r[2] = (bf16_t)a.z; r[3] = (bf16_t)a.w;
    r[4] = (bf16_t)b.x; r[5] = (bf16_t)b.y; r[6] = (bf16_t)b.z; r[7] = (bf16_t)b.w;
    return r;
}

__global__ __launch_bounds__(256) __attribute__((amdgpu_waves_per_eu(2, 2)))
void head_attn_kernel(const float* __restrict__ x,
                      const float* __restrict__ Wq,
                      const float* __restrict__ Wk,
                      const float* __restrict__ Wv,
                      float* __restrict__ out,
                      int NB)
{
    __shared__ __align__(16) char smem[LDS_BYTES];
    const int tid  = threadIdx.x;
    const int w    = tid >> 6;
    const int lane = tid & 63;
    const int l15  = lane & 15;
    const int lg   = lane >> 4;
    const int t    = w * 16 + l15;          // lane's owned query/time row
    char* qscr = smem + QS_OFF + w * 2048;

    // ---- stage W -> LDS once, pre-permuted into per-lane 16B fragments ----
    // chunk c = (ks*12 + j)*64 + ln holds W[h = j*16 + (ln&15)][ks*32+(ln>>4)*8 ..+8)
    #pragma unroll
    for (int i = 0; i < 12; ++i) {
        int c   = i * 256 + tid;
        int ks  = i / 3;                      // == c/768 (compile-time per i)
        int rem = c - ks * 768;
        int j   = rem >> 6;
        int ln  = rem & 63;
        int h   = j * 16 + (ln & 15);
        int c0  = ks * 32 + (ln >> 4) * 8;
        const float* wr = (h < 64)  ? Wq + h * 128
                        : (h < 128) ? Wk + (h - 64) * 128
                                    : Wv + (h - 128) * 128;
        float4 a  = *(const float4*)(wr + c0);
        float4 bb = *(const float4*)(wr + c0 + 4);
        *(bf16x8*)(smem + WL_OFF + c * 16) = pack8(a, bb);
    }

    // ---- prefetch first batch's x row (8 independent float4, 32 VGPRs) ----
    const size_t b0 = (size_t)blockIdx.x * NB;
    const float* xrow = x + b0 * 8192 + t * 128 + lg * 8;
    float4 xr[8];
    #pragma unroll
    for (int k = 0; k < 8; ++k)
        xr[k] = *(const float4*)(xrow + (k >> 1) * 32 + (k & 1) * 4);

    lds_barrier();   // W staged; batch-0 prefetch stays in flight

    for (int i = 0; i < NB; ++i) {
        // current batch's x -> bf16 MFMA fragments (vmcnt waited HERE, not at
        // the previous barrier -- issued a full iteration ago, fully hidden)
        bf16x8 xb[4];
        #pragma unroll
        for (int ks = 0; ks < 4; ++ks) xb[ks] = pack8(xr[2 * ks], xr[2 * ks + 1]);

        // issue next batch's x loads (stay in flight across both barriers)
        if (i + 1 < NB) {
            const float* xn = xrow + (size_t)(i + 1) * 8192;
            #pragma unroll
            for (int k = 0; k < 8; ++k)
                xr[k] = *(const float4*)(xn + (k >> 1) * 32 + (k & 1) * 4);
        }

        // ------------- QKV: all 12 h-tiles for this wave's t-tile ----------
        // j 0..7 (q,k): acc = mfma(wf, xb) -> D[h][t], lane = t, regs = h
        // j 8..11 (v):  acc = mfma(xb, wf) -> D[t][h], lane = h, regs = t
        f32x4 acc[12];
        #pragma unroll
        for (int j = 0; j < 12; ++j) acc[j] = (f32x4){0.f, 0.f, 0.f, 0.f};

        #pragma unroll
        for (int ks = 0; ks < 4; ++ks) {
            bf16x8 wf[12];                    // 12 contiguous conflict-free b128
            #pragma unroll
            for (int j = 0; j < 12; ++j)
                wf[j] = *(const bf16x8*)(smem + WL_OFF + ((ks * 12 + j) * 64 + lane) * 16);
            #pragma unroll
            for (int j = 0; j < 12; ++j) {
                if (j < 8)
                    acc[j] = __builtin_amdgcn_mfma_f32_16x16x32_bf16(wf[j], xb[ks], acc[j], 0, 0, 0);
                else
                    acc[j] = __builtin_amdgcn_mfma_f32_16x16x32_bf16(xb[ks], wf[j], acc[j], 0, 0, 0);
            }
        }

        // q -> wave scratch [t_loc][h]; k -> K[s][h]; v -> VT[h][t] (all b64)
        #pragma unroll
        for (int j = 0; j < 4; ++j) {
            bf16x4 pk;
            pk[0] = (bf16_t)acc[j][0]; pk[1] = (bf16_t)acc[j][1];
            pk[2] = (bf16_t)acc[j][2]; pk[3] = (bf16_t)acc[j][3];
            *(bf16x4*)(qscr + swz(l15 * 128 + (j * 16 + lg * 4) * 2, l15)) = pk;
        }
        #pragma unroll
        for (int j = 4; j < 8; ++j) {
            bf16x4 pk;
            pk[0] = (bf16_t)acc[j][0]; pk[1] = (bf16_t)acc[j][1];
            pk[2] = (bf16_t)acc[j][2]; pk[3] = (bf16_t)acc[j][3];
            *(bf16x4*)(smem + K_OFF + swz(t * 128 + ((j - 4) * 16 + lg * 4) * 2, t)) = pk;
        }
        #pragma unroll
        for (int j = 8; j < 12; ++j) {
            int hv = (j - 8) * 16 + l15;      // acc[j][r] = V[t = w*16+lg*4+r][hv]
            bf16x4 pk;
            pk[0] = (bf16_t)acc[j][0]; pk[1] = (bf16_t)acc[j][1];
            pk[2] = (bf16_t)acc[j][2]; pk[3] = (bf16_t)acc[j][3];
            *(bf16x4*)(smem + VT_OFF + swz(hv * 128 + (w * 16 + lg * 4) * 2, hv)) = pk;
        }
        lds_barrier();   // publish q/k/v; x prefetch NOT drained

        // ------------- S^T = K . q^T : lane = col t (own row), regs = s ----
        f32x4 sacc[4];
        #pragma unroll
        for (int st = 0; st < 4; ++st) sacc[st] = (f32x4){0.f, 0.f, 0.f, 0.f};
        #pragma unroll
        for (int ks = 0; ks < 2; ++ks) {
            int h0 = ks * 32 + lg * 8;
            bf16x8 qf = *(const bf16x8*)(qscr + swz(l15 * 128 + h0 * 2, l15));
            #pragma unroll
            for (int st = 0; st < 4; ++st) {
                int s = st * 16 + l15;
                bf16x8 kf = *(const bf16x8*)(smem + K_OFF + swz(s * 128 + h0 * 2, s));
                sacc[st] = __builtin_amdgcn_mfma_f32_16x16x32_bf16(kf, qf, sacc[st], 0, 0, 0);
            }
        }

        // ------------- softmax: each lane owns full row t ------------------
        float p[4][4];
        float m = -1e30f;
        #pragma unroll
        for (int st = 0; st < 4; ++st)
            #pragma unroll
            for (int r = 0; r < 4; ++r) {
                int s = st * 16 + lg * 4 + r;
                float v = sacc[st][r] * 0.125f;
                v = (s <= t) ? v : -1e30f;     // causal
                p[st][r] = v;
                m = fmaxf(m, v);
            }
        m = fmaxf(m, __shfl_xor(m, 16));
        m = fmaxf(m, __shfl_xor(m, 32));
        float sum = 0.f;
        #pragma unroll
        for (int st = 0; st < 4; ++st)
            #pragma unroll
            for (int r = 0; r < 4; ++r) {
                float e = __expf(p[st][r] - m);
                p[st][r] = e;
                sum += e;
            }
        sum += __shfl_xor(sum, 16);
        sum += __shfl_xor(sum, 32);
        float inv = 1.0f / sum;
        #pragma unroll
        for (int st = 0; st < 4; ++st) {
            bf16x4 pk;
            pk[0] = (bf16_t)(p[st][0] * inv); pk[1] = (bf16_t)(p[st][1] * inv);
            pk[2] = (bf16_t)(p[st][2] * inv); pk[3] = (bf16_t)(p[st][3] * inv);
            *(bf16x4*)(qscr + swz(l15 * 128 + (st * 16 + lg * 4) * 2, l15)) = pk;
        }
        // wave-private scratch: same-wave write->read, in-order, no barrier

        // ------------- out^T = V^T . P^T (swapped): lane = col t -----------
        f32x4 oacc[4];
        #pragma unroll
        for (int ht = 0; ht < 4; ++ht) oacc[ht] = (f32x4){0.f, 0.f, 0.f, 0.f};
        #pragma unroll
        for (int ks = 0; ks < 2; ++ks) {
            int s0 = ks * 32 + lg * 8;
            bf16x8 pf = *(const bf16x8*)(qscr + swz(l15 * 128 + s0 * 2, l15));
            #pragma unroll
            for (int ht = 0; ht < 4; ++ht) {
                int h = ht * 16 + l15;
                bf16x8 vf = *(const bf16x8*)(smem + VT_OFF + swz(h * 128 + s0 * 2, h));
                oacc[ht] = __builtin_amdgcn_mfma_f32_16x16x32_bf16(vf, pf, oacc[ht], 0, 0, 0);
            }
        }

        float* ob = out + (b0 + i) * 4096 + t * 64 + lg * 4;
        #pragma unroll
        for (int ht = 0; ht < 4; ++ht)
            *(float4*)(ob + ht * 16) =
                (float4){oacc[ht][0], oacc[ht][1], oacc[ht][2], oacc[ht][3]};

        lds_barrier();   // K/VT/QS reads done; stores + x prefetch in flight
    }
}

extern "C" void kernel_launch(void* const* d_in, const int* in_sizes, int n_in,
                              void* d_out, int out_size, void* d_ws, size_t ws_size,
                              hipStream_t stream) {
    const float* x  = (const float*)d_in[0];
    const float* Wq = (const float*)d_in[1];
    const float* Wk = (const float*)d_in[2];
    const float* Wv = (const float*)d_in[3];
    float* out = (float*)d_out;
    int B = in_sizes[0] / (64 * 128);   // 4096
    int grid = 512;                     // 2 blocks/CU
    int NB = B / grid;                  // 8 batches per block
    head_attn_kernel<<<grid, 256, 0, stream>>>(x, Wq, Wk, Wv, out, NB);
}